// Round 3
// baseline (10150.385 us; speedup 1.0000x reference)
//
#include <hip/hip_runtime.h>
#include <hip/hip_bf16.h>

typedef unsigned short u16;
typedef unsigned int u32;
typedef __attribute__((ext_vector_type(8))) short short8;
typedef __attribute__((ext_vector_type(4))) float f32x4;
typedef __attribute__((ext_vector_type(4))) int i32x4;
typedef __attribute__((ext_vector_type(2))) unsigned u32x2;

#define SCALE_Q (1.0f/4064.0f)

__device__ __forceinline__ u16 f2bf(float f){
  union { float f; u32 u; } v; v.f = f;
  u32 r = v.u + 0x7fffu + ((v.u >> 16) & 1u);
  return (u16)(r >> 16);
}
__device__ __forceinline__ float bf2f(u16 u){
  union { u32 u; float f; } v; v.u = ((u32)u) << 16; return v.f;
}

// device-coherent (bypass L1+L2, hit IF cache) load/store helpers
__device__ __forceinline__ void ldcc_init(i32x4& r, const u32* p){
  asm volatile("global_load_dwordx4 %0, %1, off sc0 sc1" : "=v"(r) : "v"(p));
}
__device__ __forceinline__ void ldcc_re(i32x4& r, const u32* p){
  asm volatile("global_load_dwordx4 %0, %1, off sc0 sc1" : "+v"(r) : "v"(p));
}
__device__ __forceinline__ void stcc(u32* p, u32 x){
  asm volatile("global_store_dword %0, %1, off sc0 sc1" :: "v"(p), "v"(x) : "memory");
}

// ---------------------------------------------------------------------------
// prep: x fp32 -> bf16 ; w_ih_q/w_hh_q int32 -> dequant bf16
// ---------------------------------------------------------------------------
__global__ __launch_bounds__(256) void prep_kernel(
    const float* __restrict__ x, const int* __restrict__ wq, const int* __restrict__ hq,
    u16* __restrict__ xa, u16* __restrict__ wih, u16* __restrict__ whh)
{
  long i = (long)blockIdx.x*256 + threadIdx.x;
  if (i < 4194304) {                       // 16777216/4 x quads
    f32x4 v = ((const f32x4*)x)[i];
    u32x2 o;
    o[0] = (u32)f2bf(v[0]) | ((u32)f2bf(v[1]) << 16);
    o[1] = (u32)f2bf(v[2]) | ((u32)f2bf(v[3]) << 16);
    ((u32x2*)xa)[i] = o;
  } else if (i < 6553600) {                // + 9437184/4 w_ih quads
    long k = i - 4194304;
    i32x4 q = ((const i32x4*)wq)[k];
    u32x2 o;
    o[0] = (u32)f2bf((q[0]-128)*SCALE_Q) | ((u32)f2bf((q[1]-128)*SCALE_Q) << 16);
    o[1] = (u32)f2bf((q[2]-128)*SCALE_Q) | ((u32)f2bf((q[3]-128)*SCALE_Q) << 16);
    ((u32x2*)wih)[k] = o;
  } else if (i < 7733248) {                // + 4718592/4 w_hh quads
    long k = i - 6553600;
    i32x4 q = ((const i32x4*)hq)[k];
    u32x2 o;
    o[0] = (u32)f2bf((q[0]-128)*SCALE_Q) | ((u32)f2bf((q[1]-128)*SCALE_Q) << 16);
    o[1] = (u32)f2bf((q[2]-128)*SCALE_Q) | ((u32)f2bf((q[3]-128)*SCALE_Q) << 16);
    ((u32x2*)whh)[k] = o;
  }
}

// ---------------------------------------------------------------------------
// gemm: gi = X(16384x1024 bf16) @ W^T(3072x1024 bf16) + bih (+bhh for r,z)
// C written bf16 in consumer-major layout [d][s][jg16][b32][gate3][jl32]
// ---------------------------------------------------------------------------
__global__ __launch_bounds__(256) void gemm_gi_kernel(
    const u16* __restrict__ X,
    const u16* __restrict__ W,
    const float* __restrict__ bih,
    const float* __restrict__ bhh,
    u16* __restrict__ gi)
{
  __shared__ u16 As[128][40];
  __shared__ u16 Bs[128][40];
  const int tid = threadIdx.x;
  const int wv = tid >> 6, l = tid & 63;
  const int wm = wv >> 1, wn = wv & 1;
  const int fr = l & 15, kg = l >> 4;
  const int n0 = blockIdx.x << 7, m0 = blockIdx.y << 7;
  const int sr = tid >> 1, sc = (tid & 1) << 4;
  const u16* Ag = X + (long)(m0 + sr)*1024 + sc;
  const u16* Bg = W + (long)(n0 + sr)*1024 + sc;
  f32x4 acc[4][4];
  for (int i = 0; i < 4; ++i)
    for (int j = 0; j < 4; ++j) acc[i][j] = (f32x4){0.f,0.f,0.f,0.f};

  for (int kt = 0; kt < 1024; kt += 32) {
    short8 a0 = *(const short8*)(Ag + kt);
    short8 a1 = *(const short8*)(Ag + kt + 8);
    short8 b0 = *(const short8*)(Bg + kt);
    short8 b1 = *(const short8*)(Bg + kt + 8);
    __syncthreads();
    *(short8*)&As[sr][sc]   = a0; *(short8*)&As[sr][sc+8] = a1;
    *(short8*)&Bs[sr][sc]   = b0; *(short8*)&Bs[sr][sc+8] = b1;
    __syncthreads();
    short8 af[4], bf_[4];
    for (int mi = 0; mi < 4; ++mi) af[mi]  = *(const short8*)&As[(wm<<6)+(mi<<4)+fr][kg<<3];
    for (int ni = 0; ni < 4; ++ni) bf_[ni] = *(const short8*)&Bs[(wn<<6)+(ni<<4)+fr][kg<<3];
    for (int mi = 0; mi < 4; ++mi)
      for (int ni = 0; ni < 4; ++ni)
        acc[mi][ni] = __builtin_amdgcn_mfma_f32_16x16x32_bf16(af[mi], bf_[ni], acc[mi][ni], 0, 0, 0);
  }

  for (int mi = 0; mi < 4; ++mi) {
    int gmb = m0 + (wm<<6) + (mi<<4) + (kg<<2);
    for (int ni = 0; ni < 4; ++ni) {
      int gn = n0 + (wn<<6) + (ni<<4) + fr;
      int dd = (gn >= 1536) ? 1 : 0;
      int rem = gn - dd*1536;
      int gate = rem >> 9, j = rem & 511;
      float bs = bih[gn] + ((gate < 2) ? bhh[gn] : 0.f);
      for (int r = 0; r < 4; ++r) {
        int m = gmb + r;
        int b = m >> 9, s = m & 511;
        long addr = ((((long)dd*512 + s)*16 + (j>>5))*32 + b)*96 + (gate<<5) + (j&31);
        gi[addr] = f2bf(acc[mi][ni][r] + bs);
      }
    }
  }
}

// ---------------------------------------------------------------------------
// recurrence: 32 WGs (16 per direction), persistent over 512 steps.
// h exchange: self-tagged u32 words (bf16<<16 | tag) via sc0sc1 stores/loads,
// double-buffered by step parity. No fences, no barrier, no atomics.
// ---------------------------------------------------------------------------
__global__ __launch_bounds__(256, 1) void gru_rec_kernel(
    const u16* __restrict__ gi,     // [2][512][16][32][96]
    const u16* __restrict__ whh,    // [2][1536][512] bf16 (layer slice)
    const float* __restrict__ bhh,  // [2][1536] (only n-gate used here)
    const float* __restrict__ hx,   // [2][32][512] (layer slice)
    u16* __restrict__ xout,         // [32][512][1024] bf16 or null
    float* __restrict__ ofp,        // d_out (layer 2) or null
    float* __restrict__ hfin,       // h_finals slab [2][32][512]
    u32* __restrict__ hg,           // [2 parity][2 dir][32][512] u32 tagged
    int layer)
{
  __shared__ u16 Wl[96*512];        // 96KB, XOR-swizzled
  __shared__ u16 hs[32*512];        // 32KB, XOR-swizzled
  const int wg = blockIdx.x;
  const int d = wg >> 4, jg = wg & 15;
  const int j0 = jg << 5;
  const int tid = threadIdx.x;
  const int wv = tid >> 6, l = tid & 63;
  const int mt = wv & 1, jb = wv >> 1;
  const int fr = l & 15, kg = l >> 4;

  // stage Wl: rows (gate*32 + jl) <- whh[d][gate*512 + j0 + jl][:]
  {
    const u16* wbase = whh + (long)d*1536*512;
    for (int q = tid; q < 6144; q += 256) {
      int row = q >> 6, c = q & 63;
      int g = ((row >> 5) << 9) + j0 + (row & 31);
      short8 v = *(const short8*)(wbase + (long)g*512 + c*8);
      *(short8*)((char*)Wl + row*1024 + ((c*16) ^ ((row & 7) << 4))) = v;
    }
  }
  // stage hs (step 0) from hx fp32
  {
    const float* hxd = hx + (long)d*32*512;
    for (int q = tid; q < 2048; q += 256) {
      int b = q >> 6, c = q & 63;
      const float* p = hxd + (long)b*512 + c*8;
      short8 pv;
      for (int i = 0; i < 8; ++i) pv[i] = (short)f2bf(p[i]);
      *(short8*)((char*)hs + b*1024 + ((c*16) ^ ((b & 7) << 4))) = pv;
    }
  }
  const int myj = (jb << 4) + fr;
  const int gj  = j0 + myj;
  const float bh_n = bhh[d*1536 + 1024 + gj];
  const int b0 = (mt << 4) + (kg << 2);
  float h_own[4];
  for (int r = 0; r < 4; ++r)
    h_own[r] = hx[((long)d*32 + b0 + r)*512 + gj];
  __syncthreads();

  const int arow = (mt << 4) + fr;
  const int axor = (arow & 7) << 4;
  const int brow0 = (jb << 4) + fr;
  const int bx0 = (brow0 & 7) << 4;
  const int bx1 = ((brow0 + 32) & 7) << 4;
  const int bx2 = ((brow0 + 64) & 7) << 4;

  // poll-phase mapping: each thread owns 64 consecutive u32 of one h row
  const int prow = tid >> 3;
  const int pcol = (tid & 7) << 6;        // u32 index
  const int pxor = (prow & 7) << 4;

  // gi for step t=0
  float gir[4], giz[4], gin[4];
  {
    const int s0 = d ? 511 : 0;
    const u16* gp = gi + (((long)d*512 + s0)*16 + jg)*3072;
    #pragma unroll
    for (int r = 0; r < 4; ++r) {
      const u16* q = gp + (b0 + r)*96 + myj;
      gir[r] = bf2f(q[0]); giz[r] = bf2f(q[32]); gin[r] = bf2f(q[64]);
    }
  }

  for (int t = 0; t < 512; ++t) {
    const int s = d ? (511 - t) : t;
    // gh = h @ whh_slice^T
    f32x4 ar = {0.f,0.f,0.f,0.f}, az = {0.f,0.f,0.f,0.f}, an = {0.f,0.f,0.f,0.f};
    #pragma unroll
    for (int kk = 0; kk < 16; ++kk) {
      int kb = kk*64 + kg*16;
      short8 a  = *(const short8*)((const char*)hs + arow*1024 + (kb ^ axor));
      short8 w0 = *(const short8*)((const char*)Wl + brow0*1024        + (kb ^ bx0));
      short8 w1 = *(const short8*)((const char*)Wl + (brow0+32)*1024   + (kb ^ bx1));
      short8 w2 = *(const short8*)((const char*)Wl + (brow0+64)*1024   + (kb ^ bx2));
      ar = __builtin_amdgcn_mfma_f32_16x16x32_bf16(a, w0, ar, 0, 0, 0);
      az = __builtin_amdgcn_mfma_f32_16x16x32_bf16(a, w1, az, 0, 0, 0);
      an = __builtin_amdgcn_mfma_f32_16x16x32_bf16(a, w2, an, 0, 0, 0);
    }
    const u32 tag = ((u32)layer << 10) | (u32)(t + 1);
    u32* hgw = hg + (long)((t & 1)*2 + d)*32*512;
    u16 hb4[4];
    #pragma unroll
    for (int r = 0; r < 4; ++r) {
      float rr = 1.f/(1.f + __expf(-(gir[r] + ar[r])));
      float zz = 1.f/(1.f + __expf(-(giz[r] + az[r])));
      float nx = gin[r] + rr*(an[r] + bh_n);
      nx = fminf(15.f, fmaxf(-15.f, nx));
      float e = __expf(-2.f*nx);
      float nn = (1.f - e)/(1.f + e);
      float hnew = (1.f - zz)*nn + zz*h_own[r];
      h_own[r] = hnew;
      hb4[r] = f2bf(hnew);
      stcc(hgw + (b0 + r)*512 + gj, ((u32)hb4[r] << 16) | tag);  // publish ASAP
    }
    #pragma unroll
    for (int r = 0; r < 4; ++r) {
      int b = b0 + r;
      if (xout) xout[((long)b*512 + s)*1024 + (d << 9) + gj] = hb4[r];
      if (ofp)  ofp[((long)b*512 + s)*1024 + (d << 9) + gj] = h_own[r];
    }

    if (t < 511) {
      // prefetch gi for t+1 (overlaps with poll)
      float ngr[4], ngz[4], ngn[4];
      {
        const int sn = d ? (510 - t) : (t + 1);
        const u16* gp = gi + (((long)d*512 + sn)*16 + jg)*3072;
        #pragma unroll
        for (int r = 0; r < 4; ++r) {
          const u16* q = gp + (b0 + r)*96 + myj;
          ngr[r] = bf2f(q[0]); ngz[r] = bf2f(q[32]); ngn[r] = bf2f(q[64]);
        }
      }
      // poll tagged h words (this thread's 64 u32 = elements pcol..pcol+63)
      const u32* hgr = hg + (long)((t & 1)*2 + d)*32*512 + prow*512 + pcol;
      i32x4 v[16];
      #pragma unroll
      for (int c = 0; c < 16; ++c) ldcc_init(v[c], hgr + c*4);
      asm volatile("s_waitcnt vmcnt(0)" ::: "memory");
      __builtin_amdgcn_sched_barrier(0);
      u32 stale = 0;
      #pragma unroll
      for (int c = 0; c < 16; ++c) {
        u32 bad = (((u32)v[c][0]) ^ tag) & 0xFFFFu;
        bad |= (((u32)v[c][1]) ^ tag) & 0xFFFFu;
        bad |= (((u32)v[c][2]) ^ tag) & 0xFFFFu;
        bad |= (((u32)v[c][3]) ^ tag) & 0xFFFFu;
        if (bad) stale |= (1u << c);
      }
      while (stale) {
        #pragma unroll
        for (int c = 0; c < 16; ++c)
          if (stale & (1u << c)) ldcc_re(v[c], hgr + c*4);
        asm volatile("s_waitcnt vmcnt(0)" ::: "memory");
        __builtin_amdgcn_sched_barrier(0);
        u32 ns = 0;
        #pragma unroll
        for (int c = 0; c < 16; ++c) if (stale & (1u << c)) {
          u32 bad = (((u32)v[c][0]) ^ tag) & 0xFFFFu;
          bad |= (((u32)v[c][1]) ^ tag) & 0xFFFFu;
          bad |= (((u32)v[c][2]) ^ tag) & 0xFFFFu;
          bad |= (((u32)v[c][3]) ^ tag) & 0xFFFFu;
          if (bad) ns |= (1u << c);
        }
        stale = ns;
      }
      __syncthreads();                    // all threads done reading hs (step t)
      char* dst = (char*)hs + prow*1024;
      #pragma unroll
      for (int c = 0; c < 8; ++c) {
        u32 o0 = (((u32)v[2*c][0]) >> 16)   | (((u32)v[2*c][1]) & 0xFFFF0000u);
        u32 o1 = (((u32)v[2*c][2]) >> 16)   | (((u32)v[2*c][3]) & 0xFFFF0000u);
        u32 o2 = (((u32)v[2*c+1][0]) >> 16) | (((u32)v[2*c+1][1]) & 0xFFFF0000u);
        u32 o3 = (((u32)v[2*c+1][2]) >> 16) | (((u32)v[2*c+1][3]) & 0xFFFF0000u);
        i32x4 o = {(int)o0, (int)o1, (int)o2, (int)o3};
        int byte = (pcol << 1) + c*16;    // element j = pcol+8c -> byte 2*pcol+16c (FIXED)
        *(i32x4*)(dst + (byte ^ pxor)) = o;
      }
      __syncthreads();
      #pragma unroll
      for (int r = 0; r < 4; ++r) { gir[r]=ngr[r]; giz[r]=ngz[r]; gin[r]=ngn[r]; }
    }
  }
  for (int r = 0; r < 4; ++r)
    hfin[((long)d*32 + b0 + r)*512 + gj] = h_own[r];
}

// ---------------------------------------------------------------------------
// launch
// ---------------------------------------------------------------------------
extern "C" void kernel_launch(void* const* d_in, const int* in_sizes, int n_in,
                              void* d_out, int out_size, void* d_ws, size_t ws_size,
                              hipStream_t stream)
{
  const float* x   = (const float*)d_in[0];
  const float* hx  = (const float*)d_in[1];
  const int*   wihq= (const int*)d_in[2];
  const int*   whhq= (const int*)d_in[3];
  const float* bih = (const float*)d_in[4];
  const float* bhh = (const float*)d_in[5];
  float* out = (float*)d_out;
  char* ws = (char*)d_ws;

  u32* hg  = (u32*)(ws);                       //   262144 B (tagged, poison-safe)
  u16* wih = (u16*)(ws + 262144);              // 18874368 B
  u16* whh = (u16*)(ws + 19136512);            //  9437184 B
  u16* xa  = (u16*)(ws + 28573696);            // 33554432 B
  u16* xb  = (u16*)(ws + 62128128);            // 33554432 B
  u16* gi  = (u16*)(ws + 95682560);            // 100663296 B (end ~187.3 MiB)

  prep_kernel<<<30208, 256, 0, stream>>>(x, wihq, whhq, xa, wih, whh);

  for (int L_ = 0; L_ < 3; ++L_) {
    const u16* xin = (L_ & 1) ? xb : xa;
    u16* xo        = (L_ & 1) ? xa : xb;
    gemm_gi_kernel<<<dim3(24,128), 256, 0, stream>>>(
        xin, wih + (long)L_*2*1536*1024, bih + L_*3072, bhh + L_*3072, gi);
    gru_rec_kernel<<<32, 256, 0, stream>>>(
        gi, whh + (long)L_*2*1536*512, bhh + L_*3072, hx + (long)L_*2*32*512,
        (L_ == 2) ? nullptr : xo, (L_ == 2) ? out : nullptr,
        out + 16777216 + L_*32768, hg, L_);
  }
}

// Round 4
// 7124.777 us; speedup vs baseline: 1.4247x; 1.4247x over previous
//
#include <hip/hip_runtime.h>
#include <hip/hip_bf16.h>

typedef unsigned short u16;
typedef unsigned int u32;
typedef __attribute__((ext_vector_type(8))) short short8;
typedef __attribute__((ext_vector_type(4))) unsigned short u16x4;
typedef __attribute__((ext_vector_type(4))) float f32x4;
typedef __attribute__((ext_vector_type(4))) int i32x4;
typedef __attribute__((ext_vector_type(2))) unsigned u32x2;

#define SCALE_Q (1.0f/4064.0f)

__device__ __forceinline__ u16 f2bf(float f){
  union { float f; u32 u; } v; v.f = f;
  u32 r = v.u + 0x7fffu + ((v.u >> 16) & 1u);
  return (u16)(r >> 16);
}
__device__ __forceinline__ float bf2f(u16 u){
  union { u32 u; float f; } v; v.u = ((u32)u) << 16; return v.f;
}

// device-coherent (bypass L1+L2, hit IF cache) load/store helpers
__device__ __forceinline__ void ldcc_init(i32x4& r, const u32* p){
  asm volatile("global_load_dwordx4 %0, %1, off sc0 sc1" : "=&v"(r) : "v"(p));
}
__device__ __forceinline__ void ldcc_re(i32x4& r, const u32* p){
  asm volatile("global_load_dwordx4 %0, %1, off sc0 sc1" : "+v"(r) : "v"(p));
}
__device__ __forceinline__ void stcc(u32* p, u32 x){
  asm volatile("global_store_dword %0, %1, off sc0 sc1" :: "v"(p), "v"(x) : "memory");
}

// ---------------------------------------------------------------------------
// prep: x fp32 -> bf16 ; w_ih_q/w_hh_q int32 -> dequant bf16
// ---------------------------------------------------------------------------
__global__ __launch_bounds__(256) void prep_kernel(
    const float* __restrict__ x, const int* __restrict__ wq, const int* __restrict__ hq,
    u16* __restrict__ xa, u16* __restrict__ wih, u16* __restrict__ whh)
{
  long i = (long)blockIdx.x*256 + threadIdx.x;
  if (i < 4194304) {                       // 16777216/4 x quads
    f32x4 v = ((const f32x4*)x)[i];
    u32x2 o;
    o[0] = (u32)f2bf(v[0]) | ((u32)f2bf(v[1]) << 16);
    o[1] = (u32)f2bf(v[2]) | ((u32)f2bf(v[3]) << 16);
    ((u32x2*)xa)[i] = o;
  } else if (i < 6553600) {                // + 9437184/4 w_ih quads
    long k = i - 4194304;
    i32x4 q = ((const i32x4*)wq)[k];
    u32x2 o;
    o[0] = (u32)f2bf((q[0]-128)*SCALE_Q) | ((u32)f2bf((q[1]-128)*SCALE_Q) << 16);
    o[1] = (u32)f2bf((q[2]-128)*SCALE_Q) | ((u32)f2bf((q[3]-128)*SCALE_Q) << 16);
    ((u32x2*)wih)[k] = o;
  } else if (i < 7733248) {                // + 4718592/4 w_hh quads
    long k = i - 6553600;
    i32x4 q = ((const i32x4*)hq)[k];
    u32x2 o;
    o[0] = (u32)f2bf((q[0]-128)*SCALE_Q) | ((u32)f2bf((q[1]-128)*SCALE_Q) << 16);
    o[1] = (u32)f2bf((q[2]-128)*SCALE_Q) | ((u32)f2bf((q[3]-128)*SCALE_Q) << 16);
    ((u32x2*)whh)[k] = o;
  }
}

// ---------------------------------------------------------------------------
// gemm: gi = X(16384x1024 bf16) @ W^T(3072x1024 bf16) + bih (+bhh for r,z)
// C written bf16 in consumer layout [d][s][jg16][gate3][jl32][b32]
// ---------------------------------------------------------------------------
__global__ __launch_bounds__(256) void gemm_gi_kernel(
    const u16* __restrict__ X,
    const u16* __restrict__ W,
    const float* __restrict__ bih,
    const float* __restrict__ bhh,
    u16* __restrict__ gi)
{
  __shared__ u16 As[128][40];
  __shared__ u16 Bs[128][40];
  const int tid = threadIdx.x;
  const int wv = tid >> 6, l = tid & 63;
  const int wm = wv >> 1, wn = wv & 1;
  const int fr = l & 15, kg = l >> 4;
  const int n0 = blockIdx.x << 7, m0 = blockIdx.y << 7;
  const int sr = tid >> 1, sc = (tid & 1) << 4;
  const u16* Ag = X + (long)(m0 + sr)*1024 + sc;
  const u16* Bg = W + (long)(n0 + sr)*1024 + sc;
  f32x4 acc[4][4];
  for (int i = 0; i < 4; ++i)
    for (int j = 0; j < 4; ++j) acc[i][j] = (f32x4){0.f,0.f,0.f,0.f};

  for (int kt = 0; kt < 1024; kt += 32) {
    short8 a0 = *(const short8*)(Ag + kt);
    short8 a1 = *(const short8*)(Ag + kt + 8);
    short8 b0 = *(const short8*)(Bg + kt);
    short8 b1 = *(const short8*)(Bg + kt + 8);
    __syncthreads();
    *(short8*)&As[sr][sc]   = a0; *(short8*)&As[sr][sc+8] = a1;
    *(short8*)&Bs[sr][sc]   = b0; *(short8*)&Bs[sr][sc+8] = b1;
    __syncthreads();
    short8 af[4], bf_[4];
    for (int mi = 0; mi < 4; ++mi) af[mi]  = *(const short8*)&As[(wm<<6)+(mi<<4)+fr][kg<<3];
    for (int ni = 0; ni < 4; ++ni) bf_[ni] = *(const short8*)&Bs[(wn<<6)+(ni<<4)+fr][kg<<3];
    for (int mi = 0; mi < 4; ++mi)
      for (int ni = 0; ni < 4; ++ni)
        acc[mi][ni] = __builtin_amdgcn_mfma_f32_16x16x32_bf16(af[mi], bf_[ni], acc[mi][ni], 0, 0, 0);
  }

  for (int mi = 0; mi < 4; ++mi) {
    int gmb = m0 + (wm<<6) + (mi<<4) + (kg<<2);
    for (int ni = 0; ni < 4; ++ni) {
      int gn = n0 + (wn<<6) + (ni<<4) + fr;
      int dd = (gn >= 1536) ? 1 : 0;
      int rem = gn - dd*1536;
      int gate = rem >> 9, j = rem & 511;
      float bs = bih[gn] + ((gate < 2) ? bhh[gn] : 0.f);
      for (int r = 0; r < 4; ++r) {
        int m = gmb + r;
        int b = m >> 9, s = m & 511;
        long addr = ((((long)dd*512 + s)*16 + (j>>5))*3 + gate)*1024 + ((j&31)<<5) + b;
        gi[addr] = f2bf(acc[mi][ni][r] + bs);
      }
    }
  }
}

// ---------------------------------------------------------------------------
// recurrence: 32 WGs (16 per direction), persistent over 512 steps.
// W_hh slice lives in VGPRs (short8 wreg[3][16] per wave). h exchange via
// self-tagged u32 words (bf16<<16 | tag) with sc0sc1, double-buffered parity.
// Poll: wave w owns rows 8w..8w+7, lane l owns 32B at col 8l (coalesced).
// Unpack: row-uniform contiguous ds_write_b128 sweep (conflict-free).
// ---------------------------------------------------------------------------
__global__ __launch_bounds__(256, 1) void gru_rec_kernel(
    const u16* __restrict__ gi,     // [2][512][16][3][32][32]
    const u16* __restrict__ whh,    // [2][1536][512] bf16 (layer slice)
    const float* __restrict__ bhh,  // [2][1536] (only n-gate used here)
    const float* __restrict__ hx,   // [2][32][512] (layer slice)
    u16* __restrict__ xout,         // [32][512][1024] bf16 or null
    float* __restrict__ ofp,        // d_out (layer 2) or null
    float* __restrict__ hfin,       // h_finals slab [2][32][512]
    u32* __restrict__ hg,           // [2 parity][2 dir][32][512] u32 tagged
    int layer)
{
  __shared__ u16 hs[2][32*512];     // 2 x 32KB double buffer, XOR-swizzled
  const int wg = blockIdx.x;
  const int d = wg >> 4, jg = wg & 15;
  const int j0 = jg << 5;
  const int tid = threadIdx.x;
  const int wv = tid >> 6, l = tid & 63;
  const int mt = wv & 1, jb = wv >> 1;
  const int fr = l & 15, kg = l >> 4;

  // W fragments into registers: wreg[gate][kk] (192 VGPRs/lane)
  short8 wreg[3][16];
  {
    const u16* wbase = whh + (long)d*1536*512 + (long)(j0 + (jb<<4) + fr)*512 + (kg<<3);
    #pragma unroll
    for (int g = 0; g < 3; ++g)
      #pragma unroll
      for (int kk = 0; kk < 16; ++kk)
        wreg[g][kk] = *(const short8*)(wbase + (long)g*262144 + kk*32);
  }

  // stage hs[0] (step 0) from hx fp32
  {
    const float* hxd = hx + (long)d*32*512;
    for (int q = tid; q < 2048; q += 256) {
      int b = q >> 6, c = q & 63;
      const float* p = hxd + (long)b*512 + c*8;
      short8 pv;
      for (int i = 0; i < 8; ++i) pv[i] = (short)f2bf(p[i]);
      *(short8*)((char*)hs[0] + b*1024 + ((c*16) ^ ((b & 7) << 4))) = pv;
    }
  }
  const int myj = (jb << 4) + fr;
  const int gj  = j0 + myj;
  const float bh_n = bhh[d*1536 + 1024 + gj];
  const int b0 = (mt << 4) + (kg << 2);
  float h_own[4];
  for (int r = 0; r < 4; ++r)
    h_own[r] = hx[((long)d*32 + b0 + r)*512 + gj];
  __syncthreads();

  const int arow = (mt << 4) + fr;
  const int axor = (arow & 7) << 4;

  // gi regs for step t=0
  u16x4 cvr, cvz, cvn;
  {
    const int s0 = d ? 511 : 0;
    const u16* gp = gi + (((long)d*512 + s0)*16 + jg)*3072 + (myj<<5) + b0;
    cvr = *(const u16x4*)(gp);
    cvz = *(const u16x4*)(gp + 1024);
    cvn = *(const u16x4*)(gp + 2048);
  }

  for (int t = 0; t < 512; ++t) {
    const int s = d ? (511 - t) : t;
    // gh = h @ whh_slice^T  (A from LDS, B from registers)
    f32x4 ar = {0.f,0.f,0.f,0.f}, az = {0.f,0.f,0.f,0.f}, an = {0.f,0.f,0.f,0.f};
    const char* hsc = (const char*)hs[t & 1];
    #pragma unroll
    for (int kk = 0; kk < 16; ++kk) {
      int kb = kk*64 + (kg<<4);
      short8 a = *(const short8*)(hsc + arow*1024 + (kb ^ axor));
      ar = __builtin_amdgcn_mfma_f32_16x16x32_bf16(a, wreg[0][kk], ar, 0, 0, 0);
      az = __builtin_amdgcn_mfma_f32_16x16x32_bf16(a, wreg[1][kk], az, 0, 0, 0);
      an = __builtin_amdgcn_mfma_f32_16x16x32_bf16(a, wreg[2][kk], an, 0, 0, 0);
    }
    const u32 tag = ((u32)layer << 10) | (u32)(t + 1);
    u32* hgw = hg + (long)((t & 1)*2 + d)*32*512;
    u16 hb4[4];
    #pragma unroll
    for (int r = 0; r < 4; ++r) {
      float rr = 1.f/(1.f + __expf(-(bf2f(cvr[r]) + ar[r])));
      float zz = 1.f/(1.f + __expf(-(bf2f(cvz[r]) + az[r])));
      float nx = bf2f(cvn[r]) + rr*(an[r] + bh_n);
      nx = fminf(15.f, fmaxf(-15.f, nx));
      float e = __expf(-2.f*nx);
      float nn = (1.f - e)/(1.f + e);
      float hnew = (1.f - zz)*nn + zz*h_own[r];
      h_own[r] = hnew;
      hb4[r] = f2bf(hnew);
      stcc(hgw + (b0 + r)*512 + gj, ((u32)hb4[r] << 16) | tag);  // publish ASAP
    }
    #pragma unroll
    for (int r = 0; r < 4; ++r) {
      int b = b0 + r;
      if (xout) xout[((long)b*512 + s)*1024 + (d << 9) + gj] = hb4[r];
      if (ofp)  ofp[((long)b*512 + s)*1024 + (d << 9) + gj] = h_own[r];
    }

    if (t < 511) {
      // prefetch gi for t+1 (overlaps with poll)
      u16x4 nvr, nvz, nvn;
      {
        const int sn = d ? (510 - t) : (t + 1);
        const u16* gp = gi + (((long)d*512 + sn)*16 + jg)*3072 + (myj<<5) + b0;
        nvr = *(const u16x4*)(gp);
        nvz = *(const u16x4*)(gp + 1024);
        nvn = *(const u16x4*)(gp + 2048);
      }
      // poll tagged h words: wave wv owns rows 8wv..8wv+7, lane owns 32B @ col 8l
      const u32* hgr = hg + (long)((t & 1)*2 + d)*32*512 + (wv<<3)*512 + (l<<3);
      i32x4 v[16];
      #pragma unroll
      for (int i = 0; i < 8; ++i) {
        ldcc_init(v[2*i],   hgr + i*512);
        ldcc_init(v[2*i+1], hgr + i*512 + 4);
      }
      asm volatile("s_waitcnt vmcnt(0)" ::: "memory");
      __builtin_amdgcn_sched_barrier(0);
      u32 stale = 0;
      #pragma unroll
      for (int i = 0; i < 8; ++i) {
        u32 bad = (((u32)v[2*i][0]) ^ tag) & 0xFFFFu;
        bad |= (((u32)v[2*i][1]) ^ tag) & 0xFFFFu;
        bad |= (((u32)v[2*i][2]) ^ tag) & 0xFFFFu;
        bad |= (((u32)v[2*i][3]) ^ tag) & 0xFFFFu;
        bad |= (((u32)v[2*i+1][0]) ^ tag) & 0xFFFFu;
        bad |= (((u32)v[2*i+1][1]) ^ tag) & 0xFFFFu;
        bad |= (((u32)v[2*i+1][2]) ^ tag) & 0xFFFFu;
        bad |= (((u32)v[2*i+1][3]) ^ tag) & 0xFFFFu;
        if (bad) stale |= (1u << i);
      }
      while (stale) {
        #pragma unroll
        for (int i = 0; i < 8; ++i)
          if (stale & (1u << i)) {
            ldcc_re(v[2*i],   hgr + i*512);
            ldcc_re(v[2*i+1], hgr + i*512 + 4);
          }
        asm volatile("s_waitcnt vmcnt(0)" ::: "memory");
        __builtin_amdgcn_sched_barrier(0);
        u32 ns = 0;
        #pragma unroll
        for (int i = 0; i < 8; ++i) if (stale & (1u << i)) {
          u32 bad = (((u32)v[2*i][0]) ^ tag) & 0xFFFFu;
          bad |= (((u32)v[2*i][1]) ^ tag) & 0xFFFFu;
          bad |= (((u32)v[2*i][2]) ^ tag) & 0xFFFFu;
          bad |= (((u32)v[2*i][3]) ^ tag) & 0xFFFFu;
          bad |= (((u32)v[2*i+1][0]) ^ tag) & 0xFFFFu;
          bad |= (((u32)v[2*i+1][1]) ^ tag) & 0xFFFFu;
          bad |= (((u32)v[2*i+1][2]) ^ tag) & 0xFFFFu;
          bad |= (((u32)v[2*i+1][3]) ^ tag) & 0xFFFFu;
          if (bad) ns |= (1u << i);
        }
        stale = ns;
      }
      // unpack into hs[next]: row-uniform contiguous b128 sweep, conflict-free
      char* dst = (char*)hs[(t + 1) & 1];
      #pragma unroll
      for (int i = 0; i < 8; ++i) {
        u32 o0 = (((u32)v[2*i][0]) >> 16)   | (((u32)v[2*i][1]) & 0xFFFF0000u);
        u32 o1 = (((u32)v[2*i][2]) >> 16)   | (((u32)v[2*i][3]) & 0xFFFF0000u);
        u32 o2 = (((u32)v[2*i+1][0]) >> 16) | (((u32)v[2*i+1][1]) & 0xFFFF0000u);
        u32 o3 = (((u32)v[2*i+1][2]) >> 16) | (((u32)v[2*i+1][3]) & 0xFFFF0000u);
        i32x4 o = {(int)o0, (int)o1, (int)o2, (int)o3};
        *(i32x4*)(dst + (wv*8 + i)*1024 + ((l << 4) ^ (i << 4))) = o;
      }
      __syncthreads();
      cvr = nvr; cvz = nvz; cvn = nvn;
    }
  }
  for (int r = 0; r < 4; ++r)
    hfin[((long)d*32 + b0 + r)*512 + gj] = h_own[r];
}

// ---------------------------------------------------------------------------
// launch
// ---------------------------------------------------------------------------
extern "C" void kernel_launch(void* const* d_in, const int* in_sizes, int n_in,
                              void* d_out, int out_size, void* d_ws, size_t ws_size,
                              hipStream_t stream)
{
  const float* x   = (const float*)d_in[0];
  const float* hx  = (const float*)d_in[1];
  const int*   wihq= (const int*)d_in[2];
  const int*   whhq= (const int*)d_in[3];
  const float* bih = (const float*)d_in[4];
  const float* bhh = (const float*)d_in[5];
  float* out = (float*)d_out;
  char* ws = (char*)d_ws;

  u32* hg  = (u32*)(ws);                       //   262144 B (tagged, poison-safe)
  u16* wih = (u16*)(ws + 262144);              // 18874368 B
  u16* whh = (u16*)(ws + 19136512);            //  9437184 B
  u16* xa  = (u16*)(ws + 28573696);            // 33554432 B
  u16* xb  = (u16*)(ws + 62128128);            // 33554432 B
  u16* gi  = (u16*)(ws + 95682560);            // 100663296 B (end ~187.3 MiB)

  prep_kernel<<<30208, 256, 0, stream>>>(x, wihq, whhq, xa, wih, whh);

  for (int L_ = 0; L_ < 3; ++L_) {
    const u16* xin = (L_ & 1) ? xb : xa;
    u16* xo        = (L_ & 1) ? xa : xb;
    gemm_gi_kernel<<<dim3(24,128), 256, 0, stream>>>(
        xin, wih + (long)L_*2*1536*1024, bih + L_*3072, bhh + L_*3072, gi);
    gru_rec_kernel<<<32, 256, 0, stream>>>(
        gi, whh + (long)L_*2*1536*512, bhh + L_*3072, hx + (long)L_*2*32*512,
        (L_ == 2) ? nullptr : xo, (L_ == 2) ? out : nullptr,
        out + 16777216 + L_*32768, hg, L_);
  }
}